// Round 5
// baseline (61.068 us; speedup 1.0000x reference)
//
#include <hip/hip_runtime.h>

#define NCH   256
#define FH    64
#define FW    64
#define OUT_H 7
#define OUT_W 7
#define WPB   4      // waves per block
#define BANDW 40     // LDS floats per band row (>=34, pad vs conflicts)

// One wave per (roi, channel). All ROI-derived bounds are wave-uniform
// scalars (readfirstlane) -> scalar branches, no exec-mask divergence.
__global__ __launch_bounds__(256) void roipool_kernel(
    const float* __restrict__ fm,   // (B, C, H, W)
    const int*   __restrict__ rois, // (N, 5): b, x1, y1, x2, y2
    float*       __restrict__ out)  // (N, C, 7, 7)
{
    __shared__ float bands[WPB][OUT_H][BANDW];   // 4.48 KB/block

    const int tid  = threadIdx.x;
    const int wv   = tid >> 6;
    const int lane = tid & 63;
    const int stask = __builtin_amdgcn_readfirstlane(blockIdx.x * WPB + wv);
    const int sn = stask >> 8;          // roi index
    const int sc = stask & 255;         // channel

    const int* r = rois + sn * 5;       // scalar (s_load) path
    const int sb = r[0];
    const int x1 = r[1] >> 4;           // exact: x*(1/16.f) trunc, 0<=x<1024
    const int y1 = r[2] >> 4;
    const int x2 = r[3] >> 4;
    const int y2 = r[4] >> 4;
    const int h_roi = y2 - y1 + 1;      // 1..34
    const int w_roi = x2 - x1 + 1;      // 1..34, bins never empty

    // lane -> clamped region column (dup loads for lane>=w_roi hit same line)
    const int col = (lane < w_roi - 1) ? lane : (w_roi - 1);

    const float* prow = fm + (((size_t)(sb * NCH + sc)) << 12) + ((size_t)y1 << 6) + x1;
    float* bnd = &bands[wv][0][0];

    // ---- phase 1: per-column max within each of the 7 row bands ----
    // bands overlap by at most 1 row: hs_{i+1} in {he_i - 1, he_i}
    float cur = -INFINITY;
    int   i   = 0;
    int   he  = y1 + (h_roi + 6) / 7;           // he_0
    for (int row = y1; row <= y2; ++row, prow += FW) {
        const float v = prow[col];
        cur = fmaxf(cur, v);
        while (i < OUT_H && row == he - 1) {    // uniform (scalar) condition
            bnd[i * BANDW + col] = cur;         // close band i
            ++i;
            if (i < OUT_H) {
                const int hs = y1 + (i * h_roi) / 7;
                he = y1 + ((i + 1) * h_roi + 6) / 7;
                cur = (hs == row) ? v : -INFINITY;  // overlap re-seed
            }
        }
    }
    // no barrier: same wave produces and consumes its LDS slice

    // ---- phase 2: lanes 0..48 = cells; 6 clamped reads (max bin width 6) ----
    if (lane < OUT_H * OUT_W) {
        const int i2 = lane / OUT_W;
        const int j  = lane - i2 * OUT_W;
        const int ws  = (j * w_roi) / 7;
        const int we1 = ((j + 1) * w_roi + 6) / 7 - 1;    // last col, >= ws

        const float* brow = &bands[wv][i2][0];
        float m = brow[ws];
        m = fmaxf(m, brow[(ws + 1 < we1) ? ws + 1 : we1]);
        m = fmaxf(m, brow[(ws + 2 < we1) ? ws + 2 : we1]);
        m = fmaxf(m, brow[(ws + 3 < we1) ? ws + 3 : we1]);
        m = fmaxf(m, brow[(ws + 4 < we1) ? ws + 4 : we1]);
        m = fmaxf(m, brow[we1]);

        out[(size_t)stask * (OUT_H * OUT_W) + lane] = m;  // 196 B contiguous
    }
}

extern "C" void kernel_launch(void* const* d_in, const int* in_sizes, int n_in,
                              void* d_out, int out_size, void* d_ws, size_t ws_size,
                              hipStream_t stream) {
    const float* fm   = (const float*)d_in[0];
    const int*   rois = (const int*)d_in[1];
    float*       out  = (float*)d_out;

    const int N = in_sizes[1] / 5;            // 256 rois
    dim3 grid((N * NCH) / WPB);               // 16384 blocks
    dim3 block(256);
    roipool_kernel<<<grid, block, 0, stream>>>(fm, rois, out);
}

// Round 6
// 31.076 us; speedup vs baseline: 1.9651x; 1.9651x over previous
//
#include <hip/hip_runtime.h>

#define NCH   256
#define FH    64
#define FW    64
#define OUT_H 7
#define OUT_W 7
#define WPB   4      // independent waves per block
#define MAXH  34     // max region rows
#define LDSW  40     // floats per LDS row (10 quads)

__global__ __launch_bounds__(256) void roipool_kernel(
    const float* __restrict__ fm,   // (B, C, H, W)
    const int*   __restrict__ rois, // (N, 5): b, x1, y1, x2, y2
    float*       __restrict__ out)  // (N, C, 7, 7)
{
    __shared__ __align__(16) float lds[WPB][MAXH][LDSW];  // 21760 B

    const int tid  = threadIdx.x;
    const int wv   = tid >> 6;
    const int lane = tid & 63;
    const int task = __builtin_amdgcn_readfirstlane(blockIdx.x * WPB + wv);
    const int n    = task >> 8;
    const int c    = task & 255;

    const int* r = rois + n * 5;    // scalar loads (task uniform)
    const int b  = r[0];
    const int x1 = r[1] >> 4;       // exact: x*(1/16.f) trunc, 0<=x<1024
    const int y1 = r[2] >> 4;
    const int x2 = r[3] >> 4;
    const int y2 = r[4] >> 4;
    const int h_roi = y2 - y1 + 1;  // 1..34
    const int w_roi = x2 - x1 + 1;  // 1..34, bins never empty
    const int qs  = x1 >> 2;        // first aligned quad of region rows
    const int qn  = (x2 >> 2) - qs + 1;   // quads per row, 1..10
    const int off = x1 & 3;         // LDS col of x1

    // ---- stage: lane -> (row-group rr 0..5, quad qq 0..9), scalar pass trip ----
    const int rg = lane / 10;            // 0..6
    const int rr = (rg == 6) ? 0 : rg;   // lanes 60..63 duplicate (benign)
    const int qq = lane - rg * 10;       // 0..9 (0..3 for lanes 60..63)
    const int passes = (h_roi + 5) / 6;  // scalar, 1..6

    const float4* srcq =
        (const float4*)(fm + (((size_t)(b * NCH + c)) << 12) + ((size_t)y1 << 6)) + qs;
    const bool qok = (qq < qn);
    for (int p = 0; p < passes; ++p) {   // scalar trip, no divergence
        int hh = rr + p * 6;
        hh = (hh < h_roi) ? hh : (h_roi - 1);   // clamp: dup re-write, same data
        if (qok) {
            const float4 v = srcq[hh * (FW / 4) + qq];
            ((float4*)&lds[wv][hh][0])[qq] = v;
        }
    }
    // no barrier: same wave produces and consumes its LDS slice (lgkmcnt orders)

    // ---- compute: lane = cell; fixed 6x6 clamped reads (bins provably <=6x6) ----
    if (lane < OUT_H * OUT_W) {
        const int i = lane / OUT_W;
        const int j = lane - i * OUT_W;

        const int hs  = (i * h_roi) / OUT_H;
        const int he1 = ((i + 1) * h_roi + 6) / OUT_H - 1;        // last row
        const int ws  = (j * w_roi) / OUT_W + off;
        const int we1 = ((j + 1) * w_roi + 6) / OUT_W - 1 + off;  // last col

        const float* base = &lds[wv][0][0];
        float m = -INFINITY;
        #pragma unroll
        for (int a = 0; a < 6; ++a) {
            int hh = hs + a;
            hh = (hh < he1) ? hh : he1;          // clamped row (dup harmless)
            const float* rowp = base + hh * LDSW;
            #pragma unroll
            for (int bb = 0; bb < 6; ++bb) {
                int ww = ws + bb;
                ww = (ww < we1) ? ww : we1;      // clamped col (dup harmless)
                m = fmaxf(m, rowp[ww]);
            }
        }
        out[(size_t)task * (OUT_H * OUT_W) + lane] = m;  // 196 B contiguous/wave
    }
}

extern "C" void kernel_launch(void* const* d_in, const int* in_sizes, int n_in,
                              void* d_out, int out_size, void* d_ws, size_t ws_size,
                              hipStream_t stream) {
    const float* fm   = (const float*)d_in[0];
    const int*   rois = (const int*)d_in[1];
    float*       out  = (float*)d_out;

    const int N = in_sizes[1] / 5;            // 256 rois
    dim3 grid((N * NCH) / WPB);               // 16384 blocks
    dim3 block(256);
    roipool_kernel<<<grid, block, 0, stream>>>(fm, rois, out);
}

// Round 7
// 27.740 us; speedup vs baseline: 2.2015x; 1.1203x over previous
//
#include <hip/hip_runtime.h>

#define NCH   256
#define FH    64
#define FW    64
#define OUT_H 7
#define OUT_W 7
#define WPB   4      // independent waves per block
#define MAXH  34     // max region rows
#define LDSW  40     // floats per LDS row (10 quads)

__global__ __launch_bounds__(256) void roipool_kernel(
    const float* __restrict__ fm,   // (B, C, H, W)
    const int*   __restrict__ rois, // (N, 5): b, x1, y1, x2, y2
    float*       __restrict__ out)  // (N, C, 7, 7)
{
    __shared__ __align__(16) float lds[WPB][MAXH][LDSW];  // 21760 B

    const int tid  = threadIdx.x;
    const int wv   = tid >> 6;
    const int lane = tid & 63;
    const int task = __builtin_amdgcn_readfirstlane(blockIdx.x * WPB + wv);
    const int n    = task >> 8;
    const int c    = task & 255;

    const int* r = rois + n * 5;    // scalar loads (task uniform)
    const int b  = r[0];
    const int x1 = r[1] >> 4;       // exact: x*(1/16.f) trunc, 0<=x<1024
    const int y1 = r[2] >> 4;
    const int x2 = r[3] >> 4;
    const int y2 = r[4] >> 4;
    const int h_roi = y2 - y1 + 1;  // 1..34
    const int w_roi = x2 - x1 + 1;  // 1..34, bins never empty
    const int qs  = x1 >> 2;        // first aligned quad of region rows
    const int qn  = (x2 >> 2) - qs + 1;   // quads per row, 1..10
    const int off = x1 & 3;         // LDS col of x1

    // Tight SCALAR bounds on band spans: max span = q + T[r], T={0,1,2,2,2,2,2}
    const int hq = h_roi / 7, hr = h_roi - hq * 7;
    const int wq = w_roi / 7, wr = w_roi - wq * 7;
    const int hb  = hq + (hr == 0 ? 0 : (hr == 1 ? 1 : 2));   // 1..6, avg ~4
    const int wbn = wq + (wr == 0 ? 0 : (wr == 1 ? 1 : 2));   // 1..6, avg ~4

    // ---- stage: lane -> (row-group rr 0..5, quad qq 0..9), scalar pass trip ----
    const int rg = lane / 10;            // 0..6
    const int rr = (rg == 6) ? 0 : rg;   // lanes 60..63 duplicate (benign)
    const int qq = lane - rg * 10;       // 0..9 (0..3 for lanes 60..63)
    const int passes = (h_roi + 5) / 6;  // scalar, 1..6

    const float4* srcq =
        (const float4*)(fm + (((size_t)(b * NCH + c)) << 12) + ((size_t)y1 << 6)) + qs;
    const bool qok = (qq < qn);
    for (int p = 0; p < passes; ++p) {   // scalar trip
        int hh = rr + p * 6;
        hh = (hh < h_roi) ? hh : (h_roi - 1);   // clamp: dup re-write, same data
        if (qok) {
            const float4 v = srcq[hh * (FW / 4) + qq];
            ((float4*)&lds[wv][hh][0])[qq] = v;
        }
    }
    // no barrier: same wave produces and consumes its LDS slice (lgkmcnt orders)

    // ---- compute: lane = cell; scalar-trip clamped reads (avg ~4x4, max 6x6) ----
    if (lane < OUT_H * OUT_W) {
        const int i = lane / OUT_W;
        const int j = lane - i * OUT_W;

        const int hs  = (i * h_roi) / OUT_H;
        const int he1 = ((i + 1) * h_roi + 6) / OUT_H - 1;        // last row
        const int ws  = (j * w_roi) / OUT_W + off;
        const int we1 = ((j + 1) * w_roi + 6) / OUT_W - 1 + off;  // last col

        int cb[6];                      // clamped cols, compile-time indexed
        #pragma unroll
        for (int bb = 0; bb < 6; ++bb) {
            const int w = ws + bb;
            cb[bb] = (w < we1) ? w : we1;
        }

        const float* tb = &lds[wv][0][0];
        float m = -INFINITY;
        #pragma unroll
        for (int a = 0; a < 6; ++a) {
            if (a < hb) {                            // SCALAR guard (sgpr hb)
                const int hh = (hs + a < he1) ? hs + a : he1;   // lane clamp
                const float* rp = tb + hh * LDSW;
                #pragma unroll
                for (int bb = 0; bb < 6; ++bb) {
                    if (bb < wbn)                    // SCALAR guard (sgpr wbn)
                        m = fmaxf(m, rp[cb[bb]]);
                }
            }
        }
        out[(size_t)task * (OUT_H * OUT_W) + lane] = m;  // 196 B contiguous/wave
    }
}

extern "C" void kernel_launch(void* const* d_in, const int* in_sizes, int n_in,
                              void* d_out, int out_size, void* d_ws, size_t ws_size,
                              hipStream_t stream) {
    const float* fm   = (const float*)d_in[0];
    const int*   rois = (const int*)d_in[1];
    float*       out  = (float*)d_out;

    const int N = in_sizes[1] / 5;            // 256 rois
    dim3 grid((N * NCH) / WPB);               // 16384 blocks
    dim3 block(256);
    roipool_kernel<<<grid, block, 0, stream>>>(fm, rois, out);
}